// Round 6
// baseline (132.122 us; speedup 1.0000x reference)
//
#include <hip/hip_runtime.h>
#include <hip/hip_fp16.h>

#define EPSF 1e-10f

struct alignas(8) Node { int par; float c; };

typedef int      v4i  __attribute__((ext_vector_type(4)));
typedef float    v4f  __attribute__((ext_vector_type(4)));
typedef _Float16 h4   __attribute__((ext_vector_type(4)));

__device__ __forceinline__ float signed_log(float x) {
    float sg = (x > 0.f) ? 1.f : ((x < 0.f) ? -1.f : 0.f);
    return logf(fabsf(x) + EPSF) * sg;
}

// ---- Stage 1: per-CC sigmoid scores (fp16 table: 2 MB, L2-resident) ---------
__global__ void scores_kernel(const float* __restrict__ attrs,
                              const float* __restrict__ weight,
                              const float* __restrict__ bias,
                              _Float16* __restrict__ scores, int num_cc) {
    int i = blockIdx.x * blockDim.x + threadIdx.x;
    if (i >= num_cc) return;
    const float* f = attrs + (long long)i * 15;
    float w[17];
#pragma unroll
    for (int k = 0; k < 17; ++k) w[k] = weight[k];
    float acc = bias[0];
    acc += w[0] * f[0] + w[1] * f[1] + w[2] * f[2] + w[3] * f[3];
    acc += w[4] * logf(f[4]);                      // log(area)
#pragma unroll
    for (int j = 0; j < 9; ++j) acc += w[5 + j] * signed_log(f[6 + j]);
    float lshape = sqrtf(f[7]) / (sqrtf(f[6]) + EPSF);
    acc += w[14] * lshape;
    acc += w[15] * cosf(f[5]);
    acc += w[16] * sinf(f[5]);
    float sc = 1.f / (1.f + expf(-acc));
    __builtin_nontemporal_store((_Float16)sc, &scores[i]);
}

// ---- Stage 2: per-pixel contribution packed with parent (4 px / thread) -----
__global__ void pack_kernel4(const v4f* __restrict__ diff4,
                             const v4i* __restrict__ parent4,
                             const v4i* __restrict__ cc4,
                             const _Float16* __restrict__ scores,
                             v4i* __restrict__ packed2, int n4) {
    int i = blockIdx.x * blockDim.x + threadIdx.x;
    if (i >= n4) return;
    v4f d = __builtin_nontemporal_load(&diff4[i]);
    v4i p = __builtin_nontemporal_load(&parent4[i]);
    v4i c = __builtin_nontemporal_load(&cc4[i]);
    float s0 = (float)scores[c.x], s1 = (float)scores[c.y];
    float s2 = (float)scores[c.z], s3 = (float)scores[c.w];
    v4i o0, o1;
    o0.x = p.x; o0.y = __float_as_int(d.x * s0);
    o0.z = p.y; o0.w = __float_as_int(d.y * s1);
    o1.x = p.z; o1.y = __float_as_int(d.z * s2);
    o1.z = p.w; o1.w = __float_as_int(d.w * s3);
    __builtin_nontemporal_store(o0, &packed2[2 * i]);
    __builtin_nontemporal_store(o1, &packed2[2 * i + 1]);
}

__global__ void pack_kernel(const float* __restrict__ diff,
                            const int* __restrict__ parent,
                            const int* __restrict__ cc_id,
                            const _Float16* __restrict__ scores,
                            Node* __restrict__ packed, int lo, int n) {
    int i = lo + blockIdx.x * blockDim.x + threadIdx.x;
    if (i >= n) return;
    Node nd;
    nd.par = parent[i];
    nd.c = diff[i] * (float)scores[cc_id[i]];
    packed[i] = nd;
}

// ---- Stage 3: range-staged chain walk (parent[i] < i) -----------------------

// Base range [0, range_end): full walk to root (parent of root == -1).
template <bool SH>
__global__ void walk_base(const Node* __restrict__ packed,
                          float* __restrict__ out,
                          _Float16* __restrict__ shadow, int range_end) {
    int i = blockIdx.x * blockDim.x + threadIdx.x;
    if (i >= range_end) return;
    long long raw = __builtin_nontemporal_load((const long long*)(packed + i));
    int cur = (int)(raw & 0xffffffffLL);
    float s = __int_as_float((int)(raw >> 32));
    while (cur >= 0) {
        Node nd = packed[cur];     // cached: 256 KB region, L2-superhot
        s += nd.c;
        cur = nd.par;
    }
    __builtin_nontemporal_store(s, &out[i]);
    if (SH) __builtin_nontemporal_store((_Float16)s, &shadow[i]);
}

// Phase [lo, hi): PX consecutive pixels per thread; branch-free interleaved
// chain stepping. Finished-ancestor add reads the fp16 shadow (L2-resident).
template <int PX, bool SH>
__global__ void walk_phaseN(const Node* __restrict__ packed,
                            float* __restrict__ out,
                            _Float16* __restrict__ shadow, int lo, int hi) {
    long long t = (long long)blockIdx.x * blockDim.x + threadIdx.x;
    int base = lo + (int)(t * PX);
    if (base >= hi) return;
    int cur[PX]; float s[PX];

    const bool full = (base + PX <= hi);
    if (full) {
#pragma unroll
        for (int k = 0; k < PX; k += 2) {
            v4i raw = __builtin_nontemporal_load((const v4i*)(packed + base + k));
            cur[k]     = raw.x; s[k]     = __int_as_float(raw.y);
            cur[k + 1] = raw.z; s[k + 1] = __int_as_float(raw.w);
        }
    } else {
#pragma unroll
        for (int k = 0; k < PX; ++k) {
            if (base + k < hi) { Node nd = packed[base + k]; cur[k] = nd.par; s[k] = nd.c; }
            else               { cur[k] = 0; s[k] = 0.f; }
        }
    }

    while (true) {
        bool any = false;
#pragma unroll
        for (int k = 0; k < PX; ++k) any |= (cur[k] >= lo);
        if (!__any(any)) break;
#pragma unroll
        for (int k = 0; k < PX; ++k) {
            bool act = cur[k] >= lo;
            int idx = act ? cur[k] : lo;       // dummy hot line when inactive
            Node nd = packed[idx];
            s[k]  += act ? nd.c : 0.f;
            cur[k] = act ? nd.par : cur[k];
        }
    }

    // cur[k] in [0, lo): finished (stream-ordered kernels). Shadow = fp16 copy
    // of out[0,lo): half the footprint -> per-XCD L2 resident -> low latency.
#pragma unroll
    for (int k = 0; k < PX; ++k)
        s[k] += SH ? (float)shadow[cur[k]] : out[cur[k]];

    if (full) {
#pragma unroll
        for (int k = 0; k < PX; k += 4) {
            v4f o; o.x = s[k]; o.y = s[k + 1]; o.z = s[k + 2]; o.w = s[k + 3];
            __builtin_nontemporal_store(o, (v4f*)(out + base + k));
            if (SH) {
                h4 hv; hv.x = (_Float16)s[k]; hv.y = (_Float16)s[k + 1];
                hv.z = (_Float16)s[k + 2];    hv.w = (_Float16)s[k + 3];
                __builtin_nontemporal_store(hv, (h4*)(shadow + base + k));
            }
        }
    } else {
#pragma unroll
        for (int k = 0; k < PX; ++k)
            if (base + k < hi) {
                out[base + k] = s[k];
                if (SH) shadow[base + k] = (_Float16)s[k];
            }
    }
}

// Unpacked fallbacks (only if ws too small for the packed array).
__global__ void walk_base2(const int* __restrict__ parent,
                           const float* __restrict__ contrib,
                           float* __restrict__ out, int range_end) {
    int i = blockIdx.x * blockDim.x + threadIdx.x;
    if (i >= range_end) return;
    float s = 0.f;
    int cur = i;
    while (cur >= 0) { s += contrib[cur]; cur = parent[cur]; }
    out[i] = s;
}

__global__ void walk_phase2(const int* __restrict__ parent,
                            const float* __restrict__ contrib,
                            float* __restrict__ out, int lo, int hi) {
    int i = lo + blockIdx.x * blockDim.x + threadIdx.x;
    if (i >= hi) return;
    float s = 0.f;
    int cur = i;
    while (cur >= lo) { s += contrib[cur]; cur = parent[cur]; }
    s += out[cur];
    out[i] = s;
}

__global__ void contrib_kernel(const float* __restrict__ diff,
                               const int* __restrict__ cc_id,
                               const _Float16* __restrict__ scores,
                               float* __restrict__ contrib, int n) {
    int i = blockIdx.x * blockDim.x + threadIdx.x;
    if (i >= n) return;
    contrib[i] = diff[i] * (float)scores[cc_id[i]];
}

static inline int iminh(int a, int b) { return a < b ? a : b; }

extern "C" void kernel_launch(void* const* d_in, const int* in_sizes, int n_in,
                              void* d_out, int out_size, void* d_ws, size_t ws_size,
                              hipStream_t stream) {
    const float* diff   = (const float*)d_in[0];
    const float* attrs  = (const float*)d_in[1];
    const float* weight = (const float*)d_in[2];
    const float* bias   = (const float*)d_in[3];
    const int*   parent = (const int*)d_in[4];
    const int*   cc_id  = (const int*)d_in[5];
    float* out = (float*)d_out;

    const int n      = in_sizes[0];        // 2048*2048
    const int num_cc = in_sizes[1] / 15;   // 1<<20

    _Float16* scores = (_Float16*)d_ws;    // 2 MB fp16 table
    const size_t scores_bytes = ((size_t)num_cc * sizeof(_Float16) + 255) & ~(size_t)255;
    const size_t packed_bytes = (size_t)n * sizeof(Node);
    const size_t shadow_bytes = (size_t)n * sizeof(_Float16);
    const bool use_packed = ws_size >= scores_bytes + packed_bytes;
    const bool use_shadow = ws_size >= scores_bytes + packed_bytes + shadow_bytes;

    const int TB = 256;
    scores_kernel<<<(num_cc + TB - 1) / TB, TB, 0, stream>>>(attrs, weight, bias, scores, num_cc);

    // BASE=32K: base full-walk costs ~0.3M random requests (vs 1.5M at 128K);
    // the two extra small phases add only ~0.13M. Request-rate model (r5).
    const int BASE = 32768;

    if (use_packed) {
        Node* packed = (Node*)((char*)d_ws + scores_bytes);
        _Float16* shadow = use_shadow ? (_Float16*)((char*)d_ws + scores_bytes + packed_bytes)
                                      : (_Float16*)nullptr;
        if ((n & 3) == 0) {
            pack_kernel4<<<(n / 4 + TB - 1) / TB, TB, 0, stream>>>(
                (const v4f*)diff, (const v4i*)parent, (const v4i*)cc_id, scores, (v4i*)packed, n / 4);
        } else {
            pack_kernel<<<(n + TB - 1) / TB, TB, 0, stream>>>(diff, parent, cc_id, scores, packed, 0, n);
        }
        int base_end = iminh(BASE, n);
        if (use_shadow)
            walk_base<true><<<(base_end + TB - 1) / TB, TB, 0, stream>>>(packed, out, shadow, base_end);
        else
            walk_base<false><<<(base_end + TB - 1) / TB, TB, 0, stream>>>(packed, out, shadow, base_end);
        int lo = base_end;
        while (lo < n) {                   // ratio-2 phases throughout
            long long hi_ll = (long long)lo * 2;
            int hi = (hi_ll > n) ? n : (int)hi_ll;
            int cnt = hi - lo;
            long long threads = (cnt + 3) / 4;
            int grid = (int)((threads + TB - 1) / TB);
            if (use_shadow)
                walk_phaseN<4, true><<<grid, TB, 0, stream>>>(packed, out, shadow, lo, hi);
            else
                walk_phaseN<4, false><<<grid, TB, 0, stream>>>(packed, out, shadow, lo, hi);
            lo = hi;
        }
    } else {
        float* contrib = (float*)((char*)d_ws + scores_bytes);
        contrib_kernel<<<(n + TB - 1) / TB, TB, 0, stream>>>(diff, cc_id, scores, contrib, n);
        int base_end = iminh(BASE, n);
        walk_base2<<<(base_end + TB - 1) / TB, TB, 0, stream>>>(parent, contrib, out, base_end);
        int lo = base_end;
        while (lo < n) {
            long long hi_ll = (long long)lo * 2;
            int hi = (hi_ll > n) ? n : (int)hi_ll;
            walk_phase2<<<((hi - lo) + TB - 1) / TB, TB, 0, stream>>>(parent, contrib, out, lo, hi);
            lo = hi;
        }
    }
}

// Round 7
// 127.514 us; speedup vs baseline: 1.0361x; 1.0361x over previous
//
#include <hip/hip_runtime.h>
#include <hip/hip_fp16.h>

#define EPSF 1e-10f

struct alignas(8) Node { int par; float c; };

typedef int      v4i  __attribute__((ext_vector_type(4)));
typedef float    v4f  __attribute__((ext_vector_type(4)));
typedef _Float16 h4   __attribute__((ext_vector_type(4)));

__device__ __forceinline__ float signed_log(float x) {
    float sg = (x > 0.f) ? 1.f : ((x < 0.f) ? -1.f : 0.f);
    return logf(fabsf(x) + EPSF) * sg;
}

// ---- Stage 1: per-CC sigmoid scores (fp16 table: 2 MB, L2-resident) ---------
__global__ void scores_kernel(const float* __restrict__ attrs,
                              const float* __restrict__ weight,
                              const float* __restrict__ bias,
                              _Float16* __restrict__ scores, int num_cc) {
    int i = blockIdx.x * blockDim.x + threadIdx.x;
    if (i >= num_cc) return;
    const float* f = attrs + (long long)i * 15;
    float w[17];
#pragma unroll
    for (int k = 0; k < 17; ++k) w[k] = weight[k];
    float acc = bias[0];
    acc += w[0] * f[0] + w[1] * f[1] + w[2] * f[2] + w[3] * f[3];
    acc += w[4] * logf(f[4]);                      // log(area)
#pragma unroll
    for (int j = 0; j < 9; ++j) acc += w[5 + j] * signed_log(f[6 + j]);
    float lshape = sqrtf(f[7]) / (sqrtf(f[6]) + EPSF);
    acc += w[14] * lshape;
    acc += w[15] * cosf(f[5]);
    acc += w[16] * sinf(f[5]);
    float sc = 1.f / (1.f + expf(-acc));
    __builtin_nontemporal_store((_Float16)sc, &scores[i]);
}

// ---- Prologue pack: [0, n4*4) -----------------------------------------------
__global__ void pack_kernel4(const v4f* __restrict__ diff4,
                             const v4i* __restrict__ parent4,
                             const v4i* __restrict__ cc4,
                             const _Float16* __restrict__ scores,
                             v4i* __restrict__ packed2, int n4) {
    int i = blockIdx.x * blockDim.x + threadIdx.x;
    if (i >= n4) return;
    v4f d = __builtin_nontemporal_load(&diff4[i]);
    v4i p = __builtin_nontemporal_load(&parent4[i]);
    v4i c = __builtin_nontemporal_load(&cc4[i]);
    float s0 = (float)scores[c.x], s1 = (float)scores[c.y];
    float s2 = (float)scores[c.z], s3 = (float)scores[c.w];
    v4i o0, o1;
    o0.x = p.x; o0.y = __float_as_int(d.x * s0);
    o0.z = p.y; o0.w = __float_as_int(d.y * s1);
    o1.x = p.z; o1.y = __float_as_int(d.z * s2);
    o1.z = p.w; o1.w = __float_as_int(d.w * s3);
    __builtin_nontemporal_store(o0, &packed2[2 * i]);
    __builtin_nontemporal_store(o1, &packed2[2 * i + 1]);
}

// ---- Base range [0, range_end): full walk to root (prologue packed it) ------
template <bool SH>
__global__ void walk_base(const Node* __restrict__ packed,
                          float* __restrict__ out,
                          _Float16* __restrict__ shadow, int range_end) {
    int i = blockIdx.x * blockDim.x + threadIdx.x;
    if (i >= range_end) return;
    long long raw = __builtin_nontemporal_load((const long long*)(packed + i));
    int cur = (int)(raw & 0xffffffffLL);
    float s = __int_as_float((int)(raw >> 32));
    while (cur >= 0) {
        Node nd = packed[cur];     // cached: region is small & hot (L2)
        s += nd.c;
        cur = nd.par;
    }
    __builtin_nontemporal_store(s, &out[i]);
    if (SH) __builtin_nontemporal_store((_Float16)s, &shadow[i]);
}

// ---- Fused phase: walk [lo,hi) + pack [plo,phi) (= next phase's range) ------
// Pack work (independent streams + gathers) fills the chain walk's latency
// bubbles: raises per-CU outstanding requests (Little's law lever, r6).
template <int PX, bool SH>
__global__ void walk_phase_fused(const Node* __restrict__ packed,
                                 Node* __restrict__ packed_wr,
                                 float* __restrict__ out,
                                 _Float16* __restrict__ shadow,
                                 const v4f* __restrict__ diff4,
                                 const v4i* __restrict__ parent4,
                                 const v4i* __restrict__ cc4,
                                 const _Float16* __restrict__ scores,
                                 int lo, int hi, int plo, int phi) {
    long long t = (long long)blockIdx.x * blockDim.x + threadIdx.x;
    int base = lo + (int)(t * PX);

    // ---- pack: issue streaming loads for 8 pixels of [plo, phi) early ----
    bool packv = false;
    int pbase = phi;                      // beyond range if no pack work
    v4f d0, d1; v4i pp0, pp1, cc0, cc1;
    if (phi > plo) {
        pbase = plo + (int)(t * 8);
        if (pbase + 8 <= phi) {
            int j = pbase >> 2;
            d0  = __builtin_nontemporal_load(&diff4[j]);
            d1  = __builtin_nontemporal_load(&diff4[j + 1]);
            pp0 = __builtin_nontemporal_load(&parent4[j]);
            pp1 = __builtin_nontemporal_load(&parent4[j + 1]);
            cc0 = __builtin_nontemporal_load(&cc4[j]);
            cc1 = __builtin_nontemporal_load(&cc4[j + 1]);
            packv = true;
        } else if (pbase < phi) {         // scalar tail (unaligned remainder)
            const float* df = (const float*)diff4;
            const int*   pr = (const int*)parent4;
            const int*   cc = (const int*)cc4;
            for (int k = 0; k < 8 && pbase + k < phi; ++k) {
                Node nd; nd.par = pr[pbase + k];
                nd.c = df[pbase + k] * (float)scores[cc[pbase + k]];
                packed_wr[pbase + k] = nd;
            }
        }
    }

    int cur[PX]; float s[PX];
    const bool walk = (base < hi);
    const bool full = walk && (base + PX <= hi);
    if (full) {
#pragma unroll
        for (int k = 0; k < PX; k += 2) {
            v4i raw = __builtin_nontemporal_load((const v4i*)(packed + base + k));
            cur[k]     = raw.x; s[k]     = __int_as_float(raw.y);
            cur[k + 1] = raw.z; s[k + 1] = __int_as_float(raw.w);
        }
    } else {
#pragma unroll
        for (int k = 0; k < PX; ++k) {
            if (walk && base + k < hi) { Node nd = packed[base + k]; cur[k] = nd.par; s[k] = nd.c; }
            else                       { cur[k] = lo - 1; s[k] = 0.f; }
        }
    }

    // pack: score gathers (issued before the chain loop; in flight during it)
    float ps[8];
    if (packv) {
        ps[0] = (float)scores[cc0.x]; ps[1] = (float)scores[cc0.y];
        ps[2] = (float)scores[cc0.z]; ps[3] = (float)scores[cc0.w];
        ps[4] = (float)scores[cc1.x]; ps[5] = (float)scores[cc1.y];
        ps[6] = (float)scores[cc1.z]; ps[7] = (float)scores[cc1.w];
    }

    // chain walk: branch-free interleaved stepping
    while (true) {
        bool any = false;
#pragma unroll
        for (int k = 0; k < PX; ++k) any |= (cur[k] >= lo);
        if (!__any(any)) break;
#pragma unroll
        for (int k = 0; k < PX; ++k) {
            bool act = cur[k] >= lo;
            int idx = act ? cur[k] : lo;       // dummy hot line when inactive
            Node nd = packed[idx];
            s[k]  += act ? nd.c : 0.f;
            cur[k] = act ? nd.par : cur[k];
        }
    }

    // pack: build + store (fire-and-forget)
    if (packv) {
        v4i o0, o1, o2, o3;
        o0.x = pp0.x; o0.y = __float_as_int(d0.x * ps[0]);
        o0.z = pp0.y; o0.w = __float_as_int(d0.y * ps[1]);
        o1.x = pp0.z; o1.y = __float_as_int(d0.z * ps[2]);
        o1.z = pp0.w; o1.w = __float_as_int(d0.w * ps[3]);
        o2.x = pp1.x; o2.y = __float_as_int(d1.x * ps[4]);
        o2.z = pp1.y; o2.w = __float_as_int(d1.y * ps[5]);
        o3.x = pp1.z; o3.y = __float_as_int(d1.z * ps[6]);
        o3.z = pp1.w; o3.w = __float_as_int(d1.w * ps[7]);
        v4i* dst = (v4i*)(packed_wr + pbase);
        __builtin_nontemporal_store(o0, dst);
        __builtin_nontemporal_store(o1, dst + 1);
        __builtin_nontemporal_store(o2, dst + 2);
        __builtin_nontemporal_store(o3, dst + 3);
    }

    if (!walk) return;

    // joins: cur[k] in [0, lo) finished; fp16 shadow is L2-resident
#pragma unroll
    for (int k = 0; k < PX; ++k)
        s[k] += SH ? (float)shadow[cur[k]] : out[cur[k]];

    if (full) {
#pragma unroll
        for (int k = 0; k < PX; k += 4) {
            v4f o; o.x = s[k]; o.y = s[k + 1]; o.z = s[k + 2]; o.w = s[k + 3];
            __builtin_nontemporal_store(o, (v4f*)(out + base + k));
            if (SH) {
                h4 hv; hv.x = (_Float16)s[k]; hv.y = (_Float16)s[k + 1];
                hv.z = (_Float16)s[k + 2];    hv.w = (_Float16)s[k + 3];
                __builtin_nontemporal_store(hv, (h4*)(shadow + base + k));
            }
        }
    } else {
#pragma unroll
        for (int k = 0; k < PX; ++k)
            if (base + k < hi) {
                out[base + k] = s[k];
                if (SH) shadow[base + k] = (_Float16)s[k];
            }
    }
}

// ---- Unpacked fallbacks (only if ws too small for the packed array) ---------
__global__ void walk_base2(const int* __restrict__ parent,
                           const float* __restrict__ contrib,
                           float* __restrict__ out, int range_end) {
    int i = blockIdx.x * blockDim.x + threadIdx.x;
    if (i >= range_end) return;
    float s = 0.f;
    int cur = i;
    while (cur >= 0) { s += contrib[cur]; cur = parent[cur]; }
    out[i] = s;
}

__global__ void walk_phase2(const int* __restrict__ parent,
                            const float* __restrict__ contrib,
                            float* __restrict__ out, int lo, int hi) {
    int i = lo + blockIdx.x * blockDim.x + threadIdx.x;
    if (i >= hi) return;
    float s = 0.f;
    int cur = i;
    while (cur >= lo) { s += contrib[cur]; cur = parent[cur]; }
    s += out[cur];
    out[i] = s;
}

__global__ void contrib_kernel(const float* __restrict__ diff,
                               const int* __restrict__ cc_id,
                               const _Float16* __restrict__ scores,
                               float* __restrict__ contrib, int n) {
    int i = blockIdx.x * blockDim.x + threadIdx.x;
    if (i >= n) return;
    contrib[i] = diff[i] * (float)scores[cc_id[i]];
}

static inline int iminh(int a, int b) { return a < b ? a : b; }

extern "C" void kernel_launch(void* const* d_in, const int* in_sizes, int n_in,
                              void* d_out, int out_size, void* d_ws, size_t ws_size,
                              hipStream_t stream) {
    const float* diff   = (const float*)d_in[0];
    const float* attrs  = (const float*)d_in[1];
    const float* weight = (const float*)d_in[2];
    const float* bias   = (const float*)d_in[3];
    const int*   parent = (const int*)d_in[4];
    const int*   cc_id  = (const int*)d_in[5];
    float* out = (float*)d_out;

    const int n      = in_sizes[0];        // 2048*2048
    const int num_cc = in_sizes[1] / 15;   // 1<<20

    _Float16* scores = (_Float16*)d_ws;    // 2 MB fp16 table
    const size_t scores_bytes = ((size_t)num_cc * sizeof(_Float16) + 255) & ~(size_t)255;
    const size_t packed_bytes = (size_t)n * sizeof(Node);
    const size_t shadow_bytes = (size_t)n * sizeof(_Float16);
    const bool use_packed = ws_size >= scores_bytes + packed_bytes;
    const bool use_shadow = ws_size >= scores_bytes + packed_bytes + shadow_bytes;

    const int TB = 256;
    scores_kernel<<<(num_cc + TB - 1) / TB, TB, 0, stream>>>(attrs, weight, bias, scores, num_cc);

    const int BASE = 131072;               // reverted to 128K (r6 regression)

    if (use_packed && (n & 7) == 0) {
        Node* packed = (Node*)((char*)d_ws + scores_bytes);
        _Float16* shadow = use_shadow ? (_Float16*)((char*)d_ws + scores_bytes + packed_bytes)
                                      : (_Float16*)nullptr;
        int base_end = iminh(BASE, n);
        // Prologue: pack [0, 2*BASE) (covers base walk + first fused phase)
        int pro_end = iminh(2 * base_end, n);
        pack_kernel4<<<(pro_end / 4 + TB - 1) / TB, TB, 0, stream>>>(
            (const v4f*)diff, (const v4i*)parent, (const v4i*)cc_id, scores, (v4i*)packed, pro_end / 4);
        if (use_shadow)
            walk_base<true><<<(base_end + TB - 1) / TB, TB, 0, stream>>>(packed, out, shadow, base_end);
        else
            walk_base<false><<<(base_end + TB - 1) / TB, TB, 0, stream>>>(packed, out, shadow, base_end);
        int lo = base_end;
        while (lo < n) {                   // ratio-2 phases; each packs next range
            long long hi_ll = (long long)lo * 2;
            int hi = (hi_ll > n) ? n : (int)hi_ll;
            int plo = hi;                  // pack one phase ahead
            long long phi_ll = (long long)hi * 2;
            int phi = (phi_ll > n) ? n : (int)phi_ll;
            if (phi <= pro_end) phi = plo; // already packed by prologue
            int cnt = hi - lo;
            long long threads = (cnt + 3) / 4;
            int grid = (int)((threads + TB - 1) / TB);
            if (use_shadow)
                walk_phase_fused<4, true><<<grid, TB, 0, stream>>>(
                    packed, packed, out, shadow,
                    (const v4f*)diff, (const v4i*)parent, (const v4i*)cc_id, scores,
                    lo, hi, plo, phi);
            else
                walk_phase_fused<4, false><<<grid, TB, 0, stream>>>(
                    packed, packed, out, shadow,
                    (const v4f*)diff, (const v4i*)parent, (const v4i*)cc_id, scores,
                    lo, hi, plo, phi);
            lo = hi;
        }
    } else {
        float* contrib = (float*)((char*)d_ws + scores_bytes);
        contrib_kernel<<<(n + TB - 1) / TB, TB, 0, stream>>>(diff, cc_id, scores, contrib, n);
        int base_end = iminh(BASE, n);
        walk_base2<<<(base_end + TB - 1) / TB, TB, 0, stream>>>(parent, contrib, out, base_end);
        int lo = base_end;
        while (lo < n) {
            long long hi_ll = (long long)lo * 2;
            int hi = (hi_ll > n) ? n : (int)hi_ll;
            walk_phase2<<<((hi - lo) + TB - 1) / TB, TB, 0, stream>>>(parent, contrib, out, lo, hi);
            lo = hi;
        }
    }
}

// Round 8
// 123.722 us; speedup vs baseline: 1.0679x; 1.0306x over previous
//
#include <hip/hip_runtime.h>
#include <hip/hip_fp16.h>

#define EPSF 1e-10f

struct alignas(8) Node { int par; float c; };

typedef int      v4i  __attribute__((ext_vector_type(4)));
typedef float    v4f  __attribute__((ext_vector_type(4)));
typedef _Float16 h4   __attribute__((ext_vector_type(4)));

__device__ __forceinline__ float signed_log(float x) {
    float sg = (x > 0.f) ? 1.f : ((x < 0.f) ? -1.f : 0.f);
    return logf(fabsf(x) + EPSF) * sg;
}

// ---- Stage 1: per-CC sigmoid scores (fp16 table: 2 MB) ----------------------
__global__ void scores_kernel(const float* __restrict__ attrs,
                              const float* __restrict__ weight,
                              const float* __restrict__ bias,
                              _Float16* __restrict__ scores, int num_cc) {
    int i = blockIdx.x * blockDim.x + threadIdx.x;
    if (i >= num_cc) return;
    const float* f = attrs + (long long)i * 15;
    float w[17];
#pragma unroll
    for (int k = 0; k < 17; ++k) w[k] = weight[k];
    float acc = bias[0];
    acc += w[0] * f[0] + w[1] * f[1] + w[2] * f[2] + w[3] * f[3];
    acc += w[4] * logf(f[4]);                      // log(area)
#pragma unroll
    for (int j = 0; j < 9; ++j) acc += w[5 + j] * signed_log(f[6 + j]);
    float lshape = sqrtf(f[7]) / (sqrtf(f[6]) + EPSF);
    acc += w[14] * lshape;
    acc += w[15] * cosf(f[5]);
    acc += w[16] * sinf(f[5]);
    float sc = 1.f / (1.f + expf(-acc));
    __builtin_nontemporal_store((_Float16)sc, &scores[i]);
}

// ---- Stage 2: per-pixel contribution packed with parent (4 px / thread) -----
__global__ void pack_kernel4(const v4f* __restrict__ diff4,
                             const v4i* __restrict__ parent4,
                             const v4i* __restrict__ cc4,
                             const _Float16* __restrict__ scores,
                             v4i* __restrict__ packed2, int n4) {
    int i = blockIdx.x * blockDim.x + threadIdx.x;
    if (i >= n4) return;
    v4f d = __builtin_nontemporal_load(&diff4[i]);
    v4i p = __builtin_nontemporal_load(&parent4[i]);
    v4i c = __builtin_nontemporal_load(&cc4[i]);
    float s0 = (float)scores[c.x], s1 = (float)scores[c.y];
    float s2 = (float)scores[c.z], s3 = (float)scores[c.w];
    v4i o0, o1;
    o0.x = p.x; o0.y = __float_as_int(d.x * s0);
    o0.z = p.y; o0.w = __float_as_int(d.y * s1);
    o1.x = p.z; o1.y = __float_as_int(d.z * s2);
    o1.z = p.w; o1.w = __float_as_int(d.w * s3);
    __builtin_nontemporal_store(o0, &packed2[2 * i]);
    __builtin_nontemporal_store(o1, &packed2[2 * i + 1]);
}

__global__ void pack_kernel(const float* __restrict__ diff,
                            const int* __restrict__ parent,
                            const int* __restrict__ cc_id,
                            const _Float16* __restrict__ scores,
                            Node* __restrict__ packed, int lo, int n) {
    int i = lo + blockIdx.x * blockDim.x + threadIdx.x;
    if (i >= n) return;
    Node nd;
    nd.par = parent[i];
    nd.c = diff[i] * (float)scores[cc_id[i]];
    packed[i] = nd;
}

// ---- Stage 3: range-staged chain walk (parent[i] < i) -----------------------

// Base range [0, range_end): full walk to root (parent of root == -1).
template <bool SHW>
__global__ void walk_base(const Node* __restrict__ packed,
                          float* __restrict__ out,
                          _Float16* __restrict__ shadow, int range_end) {
    int i = blockIdx.x * blockDim.x + threadIdx.x;
    if (i >= range_end) return;
    long long raw = __builtin_nontemporal_load((const long long*)(packed + i));
    int cur = (int)(raw & 0xffffffffLL);
    float s = __int_as_float((int)(raw >> 32));
    while (cur >= 0) {
        Node nd = packed[cur];     // 512 KB region, L2-hot
        s += nd.c;
        cur = nd.par;
    }
    __builtin_nontemporal_store(s, &out[i]);
    if (SHW) __builtin_nontemporal_store((_Float16)s, &shadow[i]);
}

// Phase [lo, hi): PX consecutive pixels per thread; branch-free interleaved
// chain stepping. SHR: join reads fp16 shadow; SHW: also write shadow (skip
// for the final phase -- nobody joins into it).
template <int PX, bool SHR, bool SHW>
__global__ void walk_phaseN(const Node* __restrict__ packed,
                            float* __restrict__ out,
                            _Float16* __restrict__ shadow, int lo, int hi) {
    long long t = (long long)blockIdx.x * blockDim.x + threadIdx.x;
    int base = lo + (int)(t * PX);
    if (base >= hi) return;
    int cur[PX]; float s[PX];

    const bool full = (base + PX <= hi);
    if (full) {
#pragma unroll
        for (int k = 0; k < PX; k += 2) {
            v4i raw = __builtin_nontemporal_load((const v4i*)(packed + base + k));
            cur[k]     = raw.x; s[k]     = __int_as_float(raw.y);
            cur[k + 1] = raw.z; s[k + 1] = __int_as_float(raw.w);
        }
    } else {
#pragma unroll
        for (int k = 0; k < PX; ++k) {
            if (base + k < hi) { Node nd = packed[base + k]; cur[k] = nd.par; s[k] = nd.c; }
            else               { cur[k] = 0; s[k] = 0.f; }
        }
    }

    while (true) {
        bool any = false;
#pragma unroll
        for (int k = 0; k < PX; ++k) any |= (cur[k] >= lo);
        if (!__any(any)) break;
#pragma unroll
        for (int k = 0; k < PX; ++k) {
            bool act = cur[k] >= lo;
            int idx = act ? cur[k] : lo;       // dummy hot line when inactive
            Node nd = packed[idx];
            s[k]  += act ? nd.c : 0.f;
            cur[k] = act ? nd.par : cur[k];
        }
    }

    // cur[k] in [0, lo): finished (stream-ordered kernels)
#pragma unroll
    for (int k = 0; k < PX; ++k)
        s[k] += SHR ? (float)shadow[cur[k]] : out[cur[k]];

    if (full) {
#pragma unroll
        for (int k = 0; k < PX; k += 4) {
            v4f o; o.x = s[k]; o.y = s[k + 1]; o.z = s[k + 2]; o.w = s[k + 3];
            __builtin_nontemporal_store(o, (v4f*)(out + base + k));
            if (SHW) {
                h4 hv; hv.x = (_Float16)s[k]; hv.y = (_Float16)s[k + 1];
                hv.z = (_Float16)s[k + 2];    hv.w = (_Float16)s[k + 3];
                __builtin_nontemporal_store(hv, (h4*)(shadow + base + k));
            }
        }
    } else {
#pragma unroll
        for (int k = 0; k < PX; ++k)
            if (base + k < hi) {
                out[base + k] = s[k];
                if (SHW) shadow[base + k] = (_Float16)s[k];
            }
    }
}

// ---- Unpacked fallbacks (only if ws too small for the packed array) ---------
__global__ void walk_base2(const int* __restrict__ parent,
                           const float* __restrict__ contrib,
                           float* __restrict__ out, int range_end) {
    int i = blockIdx.x * blockDim.x + threadIdx.x;
    if (i >= range_end) return;
    float s = 0.f;
    int cur = i;
    while (cur >= 0) { s += contrib[cur]; cur = parent[cur]; }
    out[i] = s;
}

__global__ void walk_phase2(const int* __restrict__ parent,
                            const float* __restrict__ contrib,
                            float* __restrict__ out, int lo, int hi) {
    int i = lo + blockIdx.x * blockDim.x + threadIdx.x;
    if (i >= hi) return;
    float s = 0.f;
    int cur = i;
    while (cur >= lo) { s += contrib[cur]; cur = parent[cur]; }
    s += out[cur];
    out[i] = s;
}

__global__ void contrib_kernel(const float* __restrict__ diff,
                               const int* __restrict__ cc_id,
                               const _Float16* __restrict__ scores,
                               float* __restrict__ contrib, int n) {
    int i = blockIdx.x * blockDim.x + threadIdx.x;
    if (i >= n) return;
    contrib[i] = diff[i] * (float)scores[cc_id[i]];
}

static inline int iminh(int a, int b) { return a < b ? a : b; }

extern "C" void kernel_launch(void* const* d_in, const int* in_sizes, int n_in,
                              void* d_out, int out_size, void* d_ws, size_t ws_size,
                              hipStream_t stream) {
    const float* diff   = (const float*)d_in[0];
    const float* attrs  = (const float*)d_in[1];
    const float* weight = (const float*)d_in[2];
    const float* bias   = (const float*)d_in[3];
    const int*   parent = (const int*)d_in[4];
    const int*   cc_id  = (const int*)d_in[5];
    float* out = (float*)d_out;

    const int n      = in_sizes[0];        // 2048*2048
    const int num_cc = in_sizes[1] / 15;   // 1<<20

    _Float16* scores = (_Float16*)d_ws;    // 2 MB fp16 table
    const size_t scores_bytes = ((size_t)num_cc * sizeof(_Float16) + 255) & ~(size_t)255;
    const size_t packed_bytes = (size_t)n * sizeof(Node);
    const size_t shadow_bytes = (size_t)n * sizeof(_Float16);
    const bool use_packed = ws_size >= scores_bytes + packed_bytes;
    const bool use_shadow = ws_size >= scores_bytes + packed_bytes + shadow_bytes;

    const int TB = 256;
    scores_kernel<<<(num_cc + TB - 1) / TB, TB, 0, stream>>>(attrs, weight, bias, scores, num_cc);

    // BASE=64K: base full-walk ~0.65M gathers (vs 1.4M at 128K); the orphaned
    // [64K,256K) range is absorbed as ONE ratio-4 phase (chain penalty ~88K
    // gathers) -- net -0.67M requests, same launch count as r4 structure.
    const int BASE = 65536;

    if (use_packed) {
        Node* packed = (Node*)((char*)d_ws + scores_bytes);
        _Float16* shadow = use_shadow ? (_Float16*)((char*)d_ws + scores_bytes + packed_bytes)
                                      : (_Float16*)nullptr;
        if ((n & 3) == 0) {
            pack_kernel4<<<(n / 4 + TB - 1) / TB, TB, 0, stream>>>(
                (const v4f*)diff, (const v4i*)parent, (const v4i*)cc_id, scores, (v4i*)packed, n / 4);
        } else {
            pack_kernel<<<(n + TB - 1) / TB, TB, 0, stream>>>(diff, parent, cc_id, scores, packed, 0, n);
        }
        int base_end = iminh(BASE, n);
        if (use_shadow && base_end < n)
            walk_base<true><<<(base_end + TB - 1) / TB, TB, 0, stream>>>(packed, out, shadow, base_end);
        else
            walk_base<false><<<(base_end + TB - 1) / TB, TB, 0, stream>>>(packed, out, shadow, base_end);
        int lo = base_end;
        bool first = true;
        while (lo < n) {
            long long mult = first ? 4 : 2;   // ratio-4 first (small), then 2
            first = false;
            long long hi_ll = (long long)lo * mult;
            int hi = (hi_ll > n) ? n : (int)hi_ll;
            int cnt = hi - lo;
            long long threads = (cnt + 3) / 4;
            int grid = (int)((threads + TB - 1) / TB);
            bool shw = use_shadow && (hi < n);   // final phase: skip shadow write
            if (use_shadow) {
                if (shw) walk_phaseN<4, true,  true ><<<grid, TB, 0, stream>>>(packed, out, shadow, lo, hi);
                else     walk_phaseN<4, true,  false><<<grid, TB, 0, stream>>>(packed, out, shadow, lo, hi);
            } else {
                walk_phaseN<4, false, false><<<grid, TB, 0, stream>>>(packed, out, shadow, lo, hi);
            }
            lo = hi;
        }
    } else {
        float* contrib = (float*)((char*)d_ws + scores_bytes);
        contrib_kernel<<<(n + TB - 1) / TB, TB, 0, stream>>>(diff, cc_id, scores, contrib, n);
        int base_end = iminh(BASE, n);
        walk_base2<<<(base_end + TB - 1) / TB, TB, 0, stream>>>(parent, contrib, out, base_end);
        int lo = base_end;
        bool first = true;
        while (lo < n) {
            long long mult = first ? 4 : 2;
            first = false;
            long long hi_ll = (long long)lo * mult;
            int hi = (hi_ll > n) ? n : (int)hi_ll;
            walk_phase2<<<((hi - lo) + TB - 1) / TB, TB, 0, stream>>>(parent, contrib, out, lo, hi);
            lo = hi;
        }
    }
}